// Round 8
// baseline (160.640 us; speedup 1.0000x reference)
//
#include <hip/hip_runtime.h>

typedef __attribute__((ext_vector_type(8))) short short8;
typedef __attribute__((ext_vector_type(4))) short short4v;
typedef __attribute__((ext_vector_type(4))) float f32x4;

#define MFMA(a, b, c) __builtin_amdgcn_mfma_f32_16x16x32_bf16((a), (b), (c), 0, 0, 0)
#define GLD16(g, l)                                                            \
  __builtin_amdgcn_global_load_lds(                                            \
      (const __attribute__((address_space(1))) void*)(g),                      \
      (__attribute__((address_space(3))) void*)(l), 16, 0, 0)

static __device__ __forceinline__ float b2f(unsigned short b) {
  union { unsigned u; float f; } u; u.u = ((unsigned)b) << 16; return u.f;
}
static __device__ __forceinline__ unsigned short f2b(float f) {
  union { float f; unsigned u; } u; u.f = f;
  unsigned r = u.u + 0x7FFFu + ((u.u >> 16) & 1u);
  return (unsigned short)(r >> 16);
}

// fp32 -> bf16 convert: [hidden][q_w][k_w][v_w][o_w] -> contiguous bf16.
__global__ __launch_bounds__(256) void convert_kernel(
    const float* __restrict__ hidden,
    const float* __restrict__ qw, const float* __restrict__ kw,
    const float* __restrict__ vw, const float* __restrict__ ow,
    unsigned short* __restrict__ dst) {
  const int HID4 = 2097152, W4 = 262144, TOT = HID4 + 4 * W4;
  for (int i = blockIdx.x * 256 + threadIdx.x; i < TOT; i += gridDim.x * 256) {
    const float* src; int off;
    if (i < HID4) { src = hidden; off = i; }
    else {
      int j = i - HID4; int w = j >> 18; off = j & (W4 - 1);
      src = (w == 0) ? qw : (w == 1) ? kw : (w == 2) ? vw : ow;
    }
    float4 v = *(const float4*)&src[(size_t)off * 4];
    short4v s;
    s[0] = (short)f2b(v.x); s[1] = (short)f2b(v.y);
    s[2] = (short)f2b(v.z); s[3] = (short)f2b(v.w);
    *(short4v*)&dst[(size_t)i * 4] = s;
  }
}

// C[8192 x N] = A[8192 x 1024](bf16) * W^T (W [N x 1024] bf16 row-major).
// 256x128 tile, BK=64, 512 thr (8 waves 4Mx2N), 3 LDS buffers, prefetch
// distance 2, counted vmcnt(6), raw barriers. QKV=true: RoPE fused epilogue.
template <bool QKV>
__global__ __launch_bounds__(512, 2) void gemm256(
    const unsigned short* __restrict__ A,
    const unsigned short* __restrict__ W,
    void* __restrict__ Cv,
    const float* __restrict__ cosb, const float* __restrict__ sinb) {
  __shared__ __align__(16) unsigned short lds[73728];
  const int tid = threadIdx.x, wave = tid >> 6, lane = tid & 63;
  const int bm = blockIdx.x << 8, bnc = blockIdx.y << 7;
  const int wr = (wave >> 1) << 6, wc = (wave & 1) << 6;
  const int lr = lane & 15, hi4 = lane >> 4;
  const int rowb = tid >> 3;
  const int cgA = (tid & 7) ^ (rowb & 7);
  const unsigned short* aSrc = A + (size_t)(bm + rowb) * 1024 + (cgA << 3);
  const unsigned short* bSrc = W + (size_t)(bnc + rowb) * 1024 + (cgA << 3);

  f32x4 acc[4][4] = {};

#define STAGE(t, bi)                                                           \
  do {                                                                         \
    unsigned short* As_ = lds + (bi) * 24576;                                  \
    unsigned short* Bs_ = As_ + 16384;                                         \
    const int k0_ = (t) << 6;                                                  \
    _Pragma("unroll") for (int i = 0; i < 4; ++i)                              \
        GLD16(aSrc + (size_t)(i << 6) * 1024 + k0_,                            \
              As_ + (((i << 9) + tid) << 3));                                  \
    _Pragma("unroll") for (int j = 0; j < 2; ++j)                              \
        GLD16(bSrc + (size_t)(j << 6) * 1024 + k0_,                            \
              Bs_ + (((j << 9) + tid) << 3));                                  \
  } while (0)

  STAGE(0, 0);
  STAGE(1, 1);
  asm volatile("s_waitcnt vmcnt(6)" ::: "memory");
  __builtin_amdgcn_s_barrier();
  __builtin_amdgcn_sched_barrier(0);

  int bi = 0;
#pragma unroll
  for (int t = 0; t < 16; ++t) {
    int pf = bi + 2; if (pf >= 3) pf -= 3;
    if (t < 14) STAGE(t + 2, pf);
    const unsigned short* As = lds + bi * 24576;
    const unsigned short* Bs = As + 16384;
    short8 af[2][4], bfr[2][4];
#pragma unroll
    for (int kk = 0; kk < 2; ++kk)
#pragma unroll
      for (int x = 0; x < 4; ++x) {
        int ra = wr + x * 16 + lr;
        af[kk][x] = *(const short8*)&As[ra * 64 + (((hi4 + kk * 4) ^ (ra & 7)) << 3)];
        int rb = wc + x * 16 + lr;
        bfr[kk][x] = *(const short8*)&Bs[rb * 64 + (((hi4 + kk * 4) ^ (rb & 7)) << 3)];
      }
    __builtin_amdgcn_s_setprio(1);
#pragma unroll
    for (int kk = 0; kk < 2; ++kk)
#pragma unroll
      for (int mm = 0; mm < 4; ++mm)
#pragma unroll
        for (int nn = 0; nn < 4; ++nn)
          acc[mm][nn] = MFMA(af[kk][mm], bfr[kk][nn], acc[mm][nn]);
    __builtin_amdgcn_s_setprio(0);
    __builtin_amdgcn_sched_barrier(0);
    if (t < 14) asm volatile("s_waitcnt vmcnt(6)" ::: "memory");
    else        asm volatile("s_waitcnt vmcnt(0)" ::: "memory");
    __builtin_amdgcn_s_barrier();
    __builtin_amdgcn_sched_barrier(0);
    if (++bi == 3) bi = 0;
  }
#undef STAGE

  const int rg = hi4 << 2;
  if constexpr (QKV) {
    const int grp = bnc >> 10;  // 0=Q 1=K 2=V
    unsigned short* Cbuf = (unsigned short*)Cv + (size_t)grp * 8388608;
    const int colbase = (bnc & 1023) + wc;
    if (grp < 2) {
      float* csf = (float*)lds;
      float* snf = csf + 8192;
#pragma unroll
      for (int i = 0; i < 4; ++i) {
        int s = (i << 9) + tid;
        int row = s >> 3, c4 = (s & 7) << 2;
        GLD16(cosb + (size_t)(bm + row) * 64 + c4, csf + s * 4);
        GLD16(sinb + (size_t)(bm + row) * 64 + c4, snf + s * 4);
      }
      asm volatile("s_waitcnt vmcnt(0)" ::: "memory");
      __builtin_amdgcn_s_barrier();
      __builtin_amdgcn_sched_barrier(0);
      const float sc = (grp == 0) ? 0.18033688011112042f : 1.0f;  // 0.125*log2e
#pragma unroll
      for (int mm = 0; mm < 4; ++mm)
#pragma unroll
        for (int r = 0; r < 4; ++r) {
          int rloc = wr + mm * 16 + rg + r;
          size_t rowoff = (size_t)(bm + rloc) * 1024;
#pragma unroll
          for (int nn = 0; nn < 2; ++nn) {
            int d = nn * 16 + lr;
            float c = csf[rloc * 32 + d], s2 = snf[rloc * 32 + d];
            float lo = acc[mm][nn][r], hi = acc[mm][nn + 2][r];
            Cbuf[rowoff + colbase + nn * 16 + lr]      = f2b((lo * c - hi * s2) * sc);
            Cbuf[rowoff + colbase + nn * 16 + lr + 32] = f2b((hi * c + lo * s2) * sc);
          }
        }
    } else {
#pragma unroll
      for (int mm = 0; mm < 4; ++mm)
#pragma unroll
        for (int nn = 0; nn < 4; ++nn)
#pragma unroll
          for (int r = 0; r < 4; ++r)
            Cbuf[(size_t)(bm + wr + mm * 16 + rg + r) * 1024 + colbase + nn * 16 + lr] =
                f2b(acc[mm][nn][r]);
    }
  } else {
    float* C = (float*)Cv;
#pragma unroll
    for (int mm = 0; mm < 4; ++mm)
#pragma unroll
      for (int nn = 0; nn < 4; ++nn)
#pragma unroll
        for (int r = 0; r < 4; ++r)
          C[(size_t)(bm + wr + mm * 16 + rg + r) * 1024 + bnc + wc + nn * 16 + lr] =
              acc[mm][nn][r];
  }
}

// Causal flash attention v4: 512 thr (8 waves x 16 q-rows = 128 q-rows/block),
// 1D grid 1024 LPT heavy-first. Dbuf K/V, d-major V staging, defer-max, exp2
// domain. Sum-reduce moved AFTER PV (co-schedules under MFMA).
__global__ __launch_bounds__(512, 4) void attn_kernel(
    const unsigned short* __restrict__ Q,
    const unsigned short* __restrict__ K,
    const unsigned short* __restrict__ V,
    unsigned short* __restrict__ O) {
  __shared__ unsigned short Ks[2][64][72];   // [buf][key][d]
  __shared__ unsigned short Vt[2][64][72];   // [buf][d][key]
  __shared__ unsigned short Ps[8][16][72];   // per-wave P
  const int tid = threadIdx.x, wave = tid >> 6, lane = tid & 63;
  const int idx = blockIdx.x;
  const int bh = idx & 127;
  const int b = bh >> 4, h = bh & 15;
  const int qb = 7 - (idx >> 7);             // heavy-first
  const int tok0 = b << 10;
  const int lr = lane & 15, hi4 = lane >> 4, lk8 = hi4 << 3;
  const int rg = hi4 << 2;
  const int qrow0 = (qb << 7) + (wave << 4); // 16 rows per wave

  short8 qf0, qf1;
  {
    const unsigned short* qp = &Q[(size_t)(tok0 + qrow0 + lr) * 1024 + h * 64];
    qf0 = *(const short8*)&qp[lk8];
    qf1 = *(const short8*)&qp[32 + lk8];
  }

  f32x4 acc[4] = {};
  float m[4], l[4];
#pragma unroll
  for (int r = 0; r < 4; ++r) { m[r] = -1e30f; l[r] = 0.f; }

  // staging over 512 threads
  const int krow = tid >> 3, kcol = (tid & 7) << 3;  // K: one b128 per thread
  const int vd = tid & 63, vko = tid >> 6;           // V: d-major, 8 scalars
  short8 kst, vst;

#define LOADT(kbx)                                                                 \
  do {                                                                             \
    const int kr0_ = tok0 + ((kbx) << 6);                                          \
    kst = *(const short8*)&K[(size_t)(kr0_ + krow) * 1024 + h * 64 + kcol];        \
    const unsigned short* vp_ = &V[(size_t)(kr0_ + (vko << 3)) * 1024 + h * 64 + vd]; \
    _Pragma("unroll") for (int i = 0; i < 8; ++i)                                  \
        vst[i] = (short)vp_[(size_t)i * 1024];                                     \
  } while (0)

#define STORET(bi)                                                                 \
  do {                                                                             \
    *(short8*)&Ks[bi][krow][kcol] = kst;                                           \
    *(short8*)&Vt[bi][vd][vko << 3] = vst;                                         \
  } while (0)

  const int nkb = (qb + 1) << 1;
  LOADT(0);
  STORET(0);
  __syncthreads();

  for (int kb = 0; kb < nkb; ++kb) {
    const int cur = kb & 1;
    const bool more = (kb + 1 < nkb);
    if (more) LOADT(kb + 1);

    float sc[4][4];
#pragma unroll
    for (int ct = 0; ct < 4; ++ct) {
      short8 kf0 = *(const short8*)&Ks[cur][ct * 16 + lr][lk8];
      short8 kf1 = *(const short8*)&Ks[cur][ct * 16 + lr][32 + lk8];
      f32x4 s = {};
      s = MFMA(qf0, kf0, s);
      s = MFMA(qf1, kf1, s);
#pragma unroll
      for (int r = 0; r < 4; ++r) sc[ct][r] = s[r];
    }
    if (kb >= 2 * qb) {
#pragma unroll
      for (int ct = 0; ct < 4; ++ct)
#pragma unroll
        for (int r = 0; r < 4; ++r) {
          int kg = (kb << 6) + ct * 16 + lr;
          int qg = qrow0 + rg + r;
          if (kg > qg) sc[ct][r] = -1e30f;
        }
    }

    float mx[4];
#pragma unroll
    for (int r = 0; r < 4; ++r)
      mx[r] = fmaxf(fmaxf(sc[0][r], sc[1][r]), fmaxf(sc[2][r], sc[3][r]));
#pragma unroll
    for (int off = 1; off < 16; off <<= 1)
#pragma unroll
      for (int r = 0; r < 4; ++r) mx[r] = fmaxf(mx[r], __shfl_xor(mx[r], off));
    // defer-max (log2 units): rescale only if some row max grew by > 8
    bool need = (mx[0] > m[0] + 8.f) | (mx[1] > m[1] + 8.f) |
                (mx[2] > m[2] + 8.f) | (mx[3] > m[3] + 8.f);
    if (__any(need)) {
#pragma unroll
      for (int r = 0; r < 4; ++r) {
        float mn = fmaxf(m[r], mx[r]);
        float alpha = __builtin_amdgcn_exp2f(m[r] - mn);
        m[r] = mn;
        l[r] *= alpha;
#pragma unroll
        for (int dt = 0; dt < 4; ++dt) acc[dt][r] *= alpha;
      }
    }
    float p[4][4];
#pragma unroll
    for (int ct = 0; ct < 4; ++ct)
#pragma unroll
      for (int r = 0; r < 4; ++r) {
        p[ct][r] = __builtin_amdgcn_exp2f(sc[ct][r] - m[r]);
        Ps[wave][rg + r][ct * 16 + lr] = f2b(p[ct][r]);
      }
    asm volatile("s_waitcnt lgkmcnt(0)" ::: "memory");
    __builtin_amdgcn_sched_barrier(0);
#pragma unroll
    for (int kk = 0; kk < 2; ++kk) {
      short8 pf = *(const short8*)&Ps[wave][lr][kk * 32 + lk8];
#pragma unroll
      for (int dt = 0; dt < 4; ++dt) {
        short8 vf = *(const short8*)&Vt[cur][dt * 16 + lr][kk * 32 + lk8];
        acc[dt] = MFMA(pf, vf, acc[dt]);
      }
    }
    // sum-reduce AFTER PV issue: co-schedules under the MFMA cluster
    float rs[4];
#pragma unroll
    for (int r = 0; r < 4; ++r)
      rs[r] = (p[0][r] + p[1][r]) + (p[2][r] + p[3][r]);
#pragma unroll
    for (int off = 1; off < 16; off <<= 1)
#pragma unroll
      for (int r = 0; r < 4; ++r) rs[r] += __shfl_xor(rs[r], off);
#pragma unroll
    for (int r = 0; r < 4; ++r) l[r] += rs[r];

    if (more) {
      STORET(cur ^ 1);
      __syncthreads();
    }
  }
#undef LOADT
#undef STORET

  float inv[4];
#pragma unroll
  for (int r = 0; r < 4; ++r) inv[r] = 1.0f / l[r];
#pragma unroll
  for (int dt = 0; dt < 4; ++dt)
#pragma unroll
    for (int r = 0; r < 4; ++r) {
      int trow = tok0 + qrow0 + rg + r;
      O[(size_t)trow * 1024 + h * 64 + dt * 16 + lr] = f2b(acc[dt][r] * inv[r]);
    }
}

extern "C" void kernel_launch(void* const* d_in, const int* in_sizes, int n_in,
                              void* d_out, int out_size, void* d_ws, size_t ws_size,
                              hipStream_t stream) {
  const float* hidden = (const float*)d_in[0];
  const float* q_w    = (const float*)d_in[1];
  const float* k_w    = (const float*)d_in[2];
  const float* v_w    = (const float*)d_in[3];
  const float* o_w    = (const float*)d_in[4];
  const float* cosb   = (const float*)d_in[5];
  const float* sinb   = (const float*)d_in[6];

  const size_t TD = (size_t)8192 * 1024;
  unsigned short* ws  = (unsigned short*)d_ws;
  unsigned short* Qb  = ws;
  unsigned short* Kb  = ws + TD;
  unsigned short* Vb  = ws + 2 * TD;
  unsigned short* hBF = ws + 3 * TD;        // hidden bf16; aliased as AO after QKV
  unsigned short* wBF = ws + 4 * TD;        // q,k,v,o weights bf16 (4 x 1M)

  convert_kernel<<<4096, 256, 0, stream>>>(hidden, q_w, k_w, v_w, o_w, hBF);
  gemm256<true><<<dim3(32, 24), 512, 0, stream>>>(hBF, wBF, Qb, cosb, sinb);
  attn_kernel<<<1024, 512, 0, stream>>>(Qb, Kb, Vb, hBF /*AO*/);
  gemm256<false><<<dim3(32, 8), 512, 0, stream>>>(
      hBF, wBF + 3 * 1048576, d_out, nullptr, nullptr);
}

// Round 9
// 160.188 us; speedup vs baseline: 1.0028x; 1.0028x over previous
//
#include <hip/hip_runtime.h>

typedef __attribute__((ext_vector_type(8))) short short8;
typedef __attribute__((ext_vector_type(4))) short short4v;
typedef __attribute__((ext_vector_type(4))) float f32x4;

#define MFMA(a, b, c) __builtin_amdgcn_mfma_f32_16x16x32_bf16((a), (b), (c), 0, 0, 0)
#define GLD16(g, l)                                                            \
  __builtin_amdgcn_global_load_lds(                                            \
      (const __attribute__((address_space(1))) void*)(g),                      \
      (__attribute__((address_space(3))) void*)(l), 16, 0, 0)

static __device__ __forceinline__ float b2f(unsigned short b) {
  union { unsigned u; float f; } u; u.u = ((unsigned)b) << 16; return u.f;
}
static __device__ __forceinline__ unsigned short f2b(float f) {
  union { float f; unsigned u; } u; u.f = f;
  unsigned r = u.u + 0x7FFFu + ((u.u >> 16) & 1u);
  return (unsigned short)(r >> 16);
}

// fp32 -> bf16 convert: [hidden][q_w][k_w][v_w][o_w] -> contiguous bf16.
__global__ __launch_bounds__(256) void convert_kernel(
    const float* __restrict__ hidden,
    const float* __restrict__ qw, const float* __restrict__ kw,
    const float* __restrict__ vw, const float* __restrict__ ow,
    unsigned short* __restrict__ dst) {
  const int HID4 = 2097152, W4 = 262144, TOT = HID4 + 4 * W4;
  for (int i = blockIdx.x * 256 + threadIdx.x; i < TOT; i += gridDim.x * 256) {
    const float* src; int off;
    if (i < HID4) { src = hidden; off = i; }
    else {
      int j = i - HID4; int w = j >> 18; off = j & (W4 - 1);
      src = (w == 0) ? qw : (w == 1) ? kw : (w == 2) ? vw : ow;
    }
    float4 v = *(const float4*)&src[(size_t)off * 4];
    short4v s;
    s[0] = (short)f2b(v.x); s[1] = (short)f2b(v.y);
    s[2] = (short)f2b(v.z); s[3] = (short)f2b(v.w);
    *(short4v*)&dst[(size_t)i * 4] = s;
  }
}

// C[8192 x N] = A[8192 x 1024](bf16) * W^T (W [N x 1024] bf16 row-major).
// 256x128 tile, BK=64, 512 thr (8 waves 4Mx2N), 3 LDS buffers, prefetch
// distance 2, counted vmcnt(6), raw barriers. QKV=true: RoPE fused epilogue.
template <bool QKV>
__global__ __launch_bounds__(512, 2) void gemm256(
    const unsigned short* __restrict__ A,
    const unsigned short* __restrict__ W,
    void* __restrict__ Cv,
    const float* __restrict__ cosb, const float* __restrict__ sinb) {
  __shared__ __align__(16) unsigned short lds[73728];
  const int tid = threadIdx.x, wave = tid >> 6, lane = tid & 63;
  const int bm = blockIdx.x << 8, bnc = blockIdx.y << 7;
  const int wr = (wave >> 1) << 6, wc = (wave & 1) << 6;
  const int lr = lane & 15, hi4 = lane >> 4;
  const int rowb = tid >> 3;
  const int cgA = (tid & 7) ^ (rowb & 7);
  const unsigned short* aSrc = A + (size_t)(bm + rowb) * 1024 + (cgA << 3);
  const unsigned short* bSrc = W + (size_t)(bnc + rowb) * 1024 + (cgA << 3);

  f32x4 acc[4][4] = {};

#define STAGE(t, bi)                                                           \
  do {                                                                         \
    unsigned short* As_ = lds + (bi) * 24576;                                  \
    unsigned short* Bs_ = As_ + 16384;                                         \
    const int k0_ = (t) << 6;                                                  \
    _Pragma("unroll") for (int i = 0; i < 4; ++i)                              \
        GLD16(aSrc + (size_t)(i << 6) * 1024 + k0_,                            \
              As_ + (((i << 9) + tid) << 3));                                  \
    _Pragma("unroll") for (int j = 0; j < 2; ++j)                              \
        GLD16(bSrc + (size_t)(j << 6) * 1024 + k0_,                            \
              Bs_ + (((j << 9) + tid) << 3));                                  \
  } while (0)

  STAGE(0, 0);
  STAGE(1, 1);
  asm volatile("s_waitcnt vmcnt(6)" ::: "memory");
  __builtin_amdgcn_s_barrier();
  __builtin_amdgcn_sched_barrier(0);

  int bi = 0;
#pragma unroll
  for (int t = 0; t < 16; ++t) {
    int pf = bi + 2; if (pf >= 3) pf -= 3;
    if (t < 14) STAGE(t + 2, pf);
    const unsigned short* As = lds + bi * 24576;
    const unsigned short* Bs = As + 16384;
    short8 af[2][4], bfr[2][4];
#pragma unroll
    for (int kk = 0; kk < 2; ++kk)
#pragma unroll
      for (int x = 0; x < 4; ++x) {
        int ra = wr + x * 16 + lr;
        af[kk][x] = *(const short8*)&As[ra * 64 + (((hi4 + kk * 4) ^ (ra & 7)) << 3)];
        int rb = wc + x * 16 + lr;
        bfr[kk][x] = *(const short8*)&Bs[rb * 64 + (((hi4 + kk * 4) ^ (rb & 7)) << 3)];
      }
    __builtin_amdgcn_s_setprio(1);
#pragma unroll
    for (int kk = 0; kk < 2; ++kk)
#pragma unroll
      for (int mm = 0; mm < 4; ++mm)
#pragma unroll
        for (int nn = 0; nn < 4; ++nn)
          acc[mm][nn] = MFMA(af[kk][mm], bfr[kk][nn], acc[mm][nn]);
    __builtin_amdgcn_s_setprio(0);
    __builtin_amdgcn_sched_barrier(0);
    if (t < 14) asm volatile("s_waitcnt vmcnt(6)" ::: "memory");
    else        asm volatile("s_waitcnt vmcnt(0)" ::: "memory");
    __builtin_amdgcn_s_barrier();
    __builtin_amdgcn_sched_barrier(0);
    if (++bi == 3) bi = 0;
  }
#undef STAGE

  const int rg = hi4 << 2;
  if constexpr (QKV) {
    const int grp = bnc >> 10;  // 0=Q 1=K 2=V
    unsigned short* Cbuf = (unsigned short*)Cv + (size_t)grp * 8388608;
    const int colbase = (bnc & 1023) + wc;
    if (grp < 2) {
      float* csf = (float*)lds;
      float* snf = csf + 8192;
#pragma unroll
      for (int i = 0; i < 4; ++i) {
        int s = (i << 9) + tid;
        int row = s >> 3, c4 = (s & 7) << 2;
        GLD16(cosb + (size_t)(bm + row) * 64 + c4, csf + s * 4);
        GLD16(sinb + (size_t)(bm + row) * 64 + c4, snf + s * 4);
      }
      asm volatile("s_waitcnt vmcnt(0)" ::: "memory");
      __builtin_amdgcn_s_barrier();
      __builtin_amdgcn_sched_barrier(0);
      const float sc = (grp == 0) ? 0.18033688011112042f : 1.0f;  // 0.125*log2e
#pragma unroll
      for (int mm = 0; mm < 4; ++mm)
#pragma unroll
        for (int r = 0; r < 4; ++r) {
          int rloc = wr + mm * 16 + rg + r;
          size_t rowoff = (size_t)(bm + rloc) * 1024;
#pragma unroll
          for (int nn = 0; nn < 2; ++nn) {
            int d = nn * 16 + lr;
            float c = csf[rloc * 32 + d], s2 = snf[rloc * 32 + d];
            float lo = acc[mm][nn][r], hi = acc[mm][nn + 2][r];
            Cbuf[rowoff + colbase + nn * 16 + lr]      = f2b((lo * c - hi * s2) * sc);
            Cbuf[rowoff + colbase + nn * 16 + lr + 32] = f2b((hi * c + lo * s2) * sc);
          }
        }
    } else {
#pragma unroll
      for (int mm = 0; mm < 4; ++mm)
#pragma unroll
        for (int nn = 0; nn < 4; ++nn)
#pragma unroll
          for (int r = 0; r < 4; ++r)
            Cbuf[(size_t)(bm + wr + mm * 16 + rg + r) * 1024 + colbase + nn * 16 + lr] =
                f2b(acc[mm][nn][r]);
    }
  } else {
    float* C = (float*)Cv;
#pragma unroll
    for (int mm = 0; mm < 4; ++mm)
#pragma unroll
      for (int nn = 0; nn < 4; ++nn)
#pragma unroll
        for (int r = 0; r < 4; ++r)
          C[(size_t)(bm + wr + mm * 16 + rg + r) * 1024 + bnc + wc + nn * 16 + lr] =
              acc[mm][nn][r];
  }
}

// Causal flash attention v5: 256 thr (4 waves x 32 q-rows), KVBLK=128,
// single-buffer LDS + T14 reg staging (load regs early, store after barrier).
// 1D grid 1024 LPT heavy-first; defer-max; exp2 domain; sum-reduce after PV.
__global__ __launch_bounds__(256, 3) void attn_kernel(
    const unsigned short* __restrict__ Q,
    const unsigned short* __restrict__ K,
    const unsigned short* __restrict__ V,
    unsigned short* __restrict__ O) {
  __shared__ unsigned short Ks[128][72];   // [key][d]
  __shared__ unsigned short Vt[64][136];   // [d][key]
  __shared__ unsigned short Ps[4][16][140];// per-wave P (stride 140: cf-free)
  const int tid = threadIdx.x, wave = tid >> 6, lane = tid & 63;
  const int idx = blockIdx.x;
  const int bh = idx & 127;
  const int b = bh >> 4, h = bh & 15;
  const int qb = 7 - (idx >> 7);           // heavy-first (LPT)
  const int tok0 = b << 10;
  const int lr = lane & 15, hi4 = lane >> 4, lk8 = hi4 << 3;
  const int rg = hi4 << 2;
  const int qrow0 = (qb << 7) + (wave << 5);  // 32 rows per wave

  short8 qf[2][2];
#pragma unroll
  for (int mt = 0; mt < 2; ++mt) {
    const unsigned short* qp = &Q[(size_t)(tok0 + qrow0 + mt * 16 + lr) * 1024 + h * 64];
#pragma unroll
    for (int kk = 0; kk < 2; ++kk) qf[mt][kk] = *(const short8*)&qp[kk * 32 + lk8];
  }

  f32x4 acc[2][4] = {};
  float m[2][4], l[2][4];
#pragma unroll
  for (int mt = 0; mt < 2; ++mt)
#pragma unroll
    for (int r = 0; r < 4; ++r) { m[mt][r] = -1e30f; l[mt][r] = 0.f; }

  // staging geometry (256 thr, 128-key tile)
  const int krow = tid >> 3, koct = (tid & 7) << 3;  // K: 4 b128 rows krow+32i
  const int vd = tid & 63, vko = (tid >> 6) << 2;    // V: d-major, octs vko..vko+3
  short8 kst[4], vst[4];

#define LOADT(tx)                                                                  \
  do {                                                                             \
    const int kr0_ = tok0 + ((tx) << 7);                                           \
    _Pragma("unroll") for (int i = 0; i < 4; ++i)                                  \
        kst[i] = *(const short8*)&K[(size_t)(kr0_ + i * 32 + krow) * 1024 +        \
                                    h * 64 + koct];                                \
    _Pragma("unroll") for (int i = 0; i < 4; ++i) {                                \
      const unsigned short* vp_ =                                                  \
          &V[(size_t)(kr0_ + ((vko + i) << 3)) * 1024 + h * 64 + vd];              \
      _Pragma("unroll") for (int j = 0; j < 8; ++j)                                \
          vst[i][j] = (short)vp_[(size_t)j * 1024];                                \
    }                                                                              \
  } while (0)

#define STORET()                                                                   \
  do {                                                                             \
    _Pragma("unroll") for (int i = 0; i < 4; ++i)                                  \
        *(short8*)&Ks[i * 32 + krow][koct] = kst[i];                               \
    _Pragma("unroll") for (int i = 0; i < 4; ++i)                                  \
        *(short8*)&Vt[vd][(vko + i) << 3] = vst[i];                                \
  } while (0)

  const int nt = qb + 1;
  LOADT(0);
  STORET();
  __syncthreads();

  for (int t = 0; t < nt; ++t) {
    const bool more = (t + 1 < nt);
    if (more) LOADT(t + 1);  // VMEM to regs; lands during compute (T14)

#pragma unroll
    for (int mt = 0; mt < 2; ++mt) {
      float sc[8][4];
#pragma unroll
      for (int ct = 0; ct < 8; ++ct) {
        short8 kf0 = *(const short8*)&Ks[ct * 16 + lr][lk8];
        short8 kf1 = *(const short8*)&Ks[ct * 16 + lr][32 + lk8];
        f32x4 s = {};
        s = MFMA(qf[mt][0], kf0, s);
        s = MFMA(qf[mt][1], kf1, s);
#pragma unroll
        for (int r = 0; r < 4; ++r) sc[ct][r] = s[r];
      }
      if (t == qb) {  // diagonal tile: mask key > q
#pragma unroll
        for (int ct = 0; ct < 8; ++ct)
#pragma unroll
          for (int r = 0; r < 4; ++r) {
            int kg = (t << 7) + ct * 16 + lr;
            int qg = qrow0 + mt * 16 + rg + r;
            if (kg > qg) sc[ct][r] = -1e30f;
          }
      }
      float mx[4];
#pragma unroll
      for (int r = 0; r < 4; ++r) {
        mx[r] = fmaxf(fmaxf(sc[0][r], sc[1][r]), fmaxf(sc[2][r], sc[3][r]));
        mx[r] = fmaxf(mx[r], fmaxf(fmaxf(sc[4][r], sc[5][r]),
                                   fmaxf(sc[6][r], sc[7][r])));
      }
#pragma unroll
      for (int off = 1; off < 16; off <<= 1)
#pragma unroll
        for (int r = 0; r < 4; ++r) mx[r] = fmaxf(mx[r], __shfl_xor(mx[r], off));
      // defer-max (log2 units)
      bool need = (mx[0] > m[mt][0] + 8.f) | (mx[1] > m[mt][1] + 8.f) |
                  (mx[2] > m[mt][2] + 8.f) | (mx[3] > m[mt][3] + 8.f);
      if (__any(need)) {
#pragma unroll
        for (int r = 0; r < 4; ++r) {
          float mn = fmaxf(m[mt][r], mx[r]);
          float alpha = __builtin_amdgcn_exp2f(m[mt][r] - mn);
          m[mt][r] = mn;
          l[mt][r] *= alpha;
#pragma unroll
          for (int dt = 0; dt < 4; ++dt) acc[mt][dt][r] *= alpha;
        }
      }
      float rs[4] = {0.f, 0.f, 0.f, 0.f};
#pragma unroll
      for (int ct = 0; ct < 8; ++ct)
#pragma unroll
        for (int r = 0; r < 4; ++r) {
          float p = __builtin_amdgcn_exp2f(sc[ct][r] - m[mt][r]);
          rs[r] += p;
          Ps[wave][rg + r][ct * 16 + lr] = f2b(p);
        }
      asm volatile("s_waitcnt lgkmcnt(0)" ::: "memory");
      __builtin_amdgcn_sched_barrier(0);
#pragma unroll
      for (int kk = 0; kk < 4; ++kk) {
        short8 pfr = *(const short8*)&Ps[wave][lr][kk * 32 + lk8];
#pragma unroll
        for (int dt = 0; dt < 4; ++dt) {
          short8 vf = *(const short8*)&Vt[dt * 16 + lr][kk * 32 + lk8];
          acc[mt][dt] = MFMA(pfr, vf, acc[mt][dt]);
        }
      }
      // sum-reduce AFTER PV issue (hides under MFMA / next mt's QK)
#pragma unroll
      for (int off = 1; off < 16; off <<= 1)
#pragma unroll
        for (int r = 0; r < 4; ++r) rs[r] += __shfl_xor(rs[r], off);
#pragma unroll
      for (int r = 0; r < 4; ++r) l[mt][r] += rs[r];
    }

    if (more) {
      __syncthreads();   // all waves done reading Ks/Vt
      STORET();          // regs -> LDS (vmcnt via data dep)
      __syncthreads();   // tile t+1 visible
    }
  }
#undef LOADT
#undef STORET

#pragma unroll
  for (int mt = 0; mt < 2; ++mt) {
    float inv[4];
#pragma unroll
    for (int r = 0; r < 4; ++r) inv[r] = 1.0f / l[mt][r];
#pragma unroll
    for (int dt = 0; dt < 4; ++dt)
#pragma unroll
      for (int r = 0; r < 4; ++r) {
        int trow = tok0 + qrow0 + mt * 16 + rg + r;
        O[(size_t)trow * 1024 + h * 64 + dt * 16 + lr] = f2b(acc[mt][dt][r] * inv[r]);
      }
  }
}

extern "C" void kernel_launch(void* const* d_in, const int* in_sizes, int n_in,
                              void* d_out, int out_size, void* d_ws, size_t ws_size,
                              hipStream_t stream) {
  const float* hidden = (const float*)d_in[0];
  const float* q_w    = (const float*)d_in[1];
  const float* k_w    = (const float*)d_in[2];
  const float* v_w    = (const float*)d_in[3];
  const float* o_w    = (const float*)d_in[4];
  const float* cosb   = (const float*)d_in[5];
  const float* sinb   = (const float*)d_in[6];

  const size_t TD = (size_t)8192 * 1024;
  unsigned short* ws  = (unsigned short*)d_ws;
  unsigned short* Qb  = ws;
  unsigned short* Kb  = ws + TD;
  unsigned short* Vb  = ws + 2 * TD;
  unsigned short* hBF = ws + 3 * TD;        // hidden bf16; aliased as AO after QKV
  unsigned short* wBF = ws + 4 * TD;        // q,k,v,o weights bf16 (4 x 1M)

  convert_kernel<<<4096, 256, 0, stream>>>(hidden, q_w, k_w, v_w, o_w, hBF);
  gemm256<true><<<dim3(32, 24), 512, 0, stream>>>(hBF, wBF, Qb, cosb, sinb);
  attn_kernel<<<1024, 256, 0, stream>>>(Qb, Kb, Vb, hBF /*AO*/);
  gemm256<false><<<dim3(32, 8), 512, 0, stream>>>(
      hBF, wBF + 3 * 1048576, d_out, nullptr, nullptr);
}

// Round 11
// 139.846 us; speedup vs baseline: 1.1487x; 1.1455x over previous
//
#include <hip/hip_runtime.h>

typedef __attribute__((ext_vector_type(8))) short short8;
typedef __attribute__((ext_vector_type(4))) short short4v;
typedef __attribute__((ext_vector_type(4))) float f32x4;

#define MFMA(a, b, c) __builtin_amdgcn_mfma_f32_16x16x32_bf16((a), (b), (c), 0, 0, 0)
#define GLD16(g, l)                                                            \
  __builtin_amdgcn_global_load_lds(                                            \
      (const __attribute__((address_space(1))) void*)(g),                      \
      (__attribute__((address_space(3))) void*)(l), 16, 0, 0)

static __device__ __forceinline__ float b2f(unsigned short b) {
  union { unsigned u; float f; } u; u.u = ((unsigned)b) << 16; return u.f;
}
static __device__ __forceinline__ unsigned short f2b(float f) {
  union { float f; unsigned u; } u; u.f = f;
  unsigned r = u.u + 0x7FFFu + ((u.u >> 16) & 1u);
  return (unsigned short)(r >> 16);
}

// fp32 -> bf16 convert: [hidden][q_w][k_w][v_w][o_w] -> contiguous bf16.
__global__ __launch_bounds__(256) void convert_kernel(
    const float* __restrict__ hidden,
    const float* __restrict__ qw, const float* __restrict__ kw,
    const float* __restrict__ vw, const float* __restrict__ ow,
    unsigned short* __restrict__ dst) {
  const int HID4 = 2097152, W4 = 262144, TOT = HID4 + 4 * W4;
  for (int i = blockIdx.x * 256 + threadIdx.x; i < TOT; i += gridDim.x * 256) {
    const float* src; int off;
    if (i < HID4) { src = hidden; off = i; }
    else {
      int j = i - HID4; int w = j >> 18; off = j & (W4 - 1);
      src = (w == 0) ? qw : (w == 1) ? kw : (w == 2) ? vw : ow;
    }
    float4 v = *(const float4*)&src[(size_t)off * 4];
    short4v s;
    s[0] = (short)f2b(v.x); s[1] = (short)f2b(v.y);
    s[2] = (short)f2b(v.z); s[3] = (short)f2b(v.w);
    *(short4v*)&dst[(size_t)i * 4] = s;
  }
}

// C[8192 x N] = A[8192 x 1024](bf16) * W^T (W [N x 1024] bf16 row-major).
// 256x128 tile, BK=64, 512 thr (8 waves 4Mx2N), 3 LDS buffers, prefetch
// distance 2, counted vmcnt(6), raw barriers. QKV=true: RoPE fused epilogue.
template <bool QKV>
__global__ __launch_bounds__(512, 2) void gemm256(
    const unsigned short* __restrict__ A,
    const unsigned short* __restrict__ W,
    void* __restrict__ Cv,
    const float* __restrict__ cosb, const float* __restrict__ sinb) {
  __shared__ __align__(16) unsigned short lds[73728];
  const int tid = threadIdx.x, wave = tid >> 6, lane = tid & 63;
  const int bm = blockIdx.x << 8, bnc = blockIdx.y << 7;
  const int wr = (wave >> 1) << 6, wc = (wave & 1) << 6;
  const int lr = lane & 15, hi4 = lane >> 4;
  const int rowb = tid >> 3;
  const int cgA = (tid & 7) ^ (rowb & 7);
  const unsigned short* aSrc = A + (size_t)(bm + rowb) * 1024 + (cgA << 3);
  const unsigned short* bSrc = W + (size_t)(bnc + rowb) * 1024 + (cgA << 3);

  f32x4 acc[4][4] = {};

#define STAGE(t, bi)                                                           \
  do {                                                                         \
    unsigned short* As_ = lds + (bi) * 24576;                                  \
    unsigned short* Bs_ = As_ + 16384;                                         \
    const int k0_ = (t) << 6;                                                  \
    _Pragma("unroll") for (int i = 0; i < 4; ++i)                              \
        GLD16(aSrc + (size_t)(i << 6) * 1024 + k0_,                            \
              As_ + (((i << 9) + tid) << 3));                                  \
    _Pragma("unroll") for (int j = 0; j < 2; ++j)                              \
        GLD16(bSrc + (size_t)(j << 6) * 1024 + k0_,                            \
              Bs_ + (((j << 9) + tid) << 3));                                  \
  } while (0)

  STAGE(0, 0);
  STAGE(1, 1);
  asm volatile("s_waitcnt vmcnt(6)" ::: "memory");
  __builtin_amdgcn_s_barrier();
  __builtin_amdgcn_sched_barrier(0);

  int bi = 0;
#pragma unroll
  for (int t = 0; t < 16; ++t) {
    int pf = bi + 2; if (pf >= 3) pf -= 3;
    if (t < 14) STAGE(t + 2, pf);
    const unsigned short* As = lds + bi * 24576;
    const unsigned short* Bs = As + 16384;
    short8 af[2][4], bfr[2][4];
#pragma unroll
    for (int kk = 0; kk < 2; ++kk)
#pragma unroll
      for (int x = 0; x < 4; ++x) {
        int ra = wr + x * 16 + lr;
        af[kk][x] = *(const short8*)&As[ra * 64 + (((hi4 + kk * 4) ^ (ra & 7)) << 3)];
        int rb = wc + x * 16 + lr;
        bfr[kk][x] = *(const short8*)&Bs[rb * 64 + (((hi4 + kk * 4) ^ (rb & 7)) << 3)];
      }
    __builtin_amdgcn_s_setprio(1);
#pragma unroll
    for (int kk = 0; kk < 2; ++kk)
#pragma unroll
      for (int mm = 0; mm < 4; ++mm)
#pragma unroll
        for (int nn = 0; nn < 4; ++nn)
          acc[mm][nn] = MFMA(af[kk][mm], bfr[kk][nn], acc[mm][nn]);
    __builtin_amdgcn_s_setprio(0);
    __builtin_amdgcn_sched_barrier(0);
    if (t < 14) asm volatile("s_waitcnt vmcnt(6)" ::: "memory");
    else        asm volatile("s_waitcnt vmcnt(0)" ::: "memory");
    __builtin_amdgcn_s_barrier();
    __builtin_amdgcn_sched_barrier(0);
    if (++bi == 3) bi = 0;
  }
#undef STAGE

  const int rg = hi4 << 2;
  if constexpr (QKV) {
    const int grp = bnc >> 10;  // 0=Q 1=K 2=V
    unsigned short* Cbuf = (unsigned short*)Cv + (size_t)grp * 8388608;
    const int colbase = (bnc & 1023) + wc;
    if (grp < 2) {
      float* csf = (float*)lds;
      float* snf = csf + 8192;
#pragma unroll
      for (int i = 0; i < 4; ++i) {
        int s = (i << 9) + tid;
        int row = s >> 3, c4 = (s & 7) << 2;
        GLD16(cosb + (size_t)(bm + row) * 64 + c4, csf + s * 4);
        GLD16(sinb + (size_t)(bm + row) * 64 + c4, snf + s * 4);
      }
      asm volatile("s_waitcnt vmcnt(0)" ::: "memory");
      __builtin_amdgcn_s_barrier();
      __builtin_amdgcn_sched_barrier(0);
      const float sc = (grp == 0) ? 0.18033688011112042f : 1.0f;  // 0.125*log2e
#pragma unroll
      for (int mm = 0; mm < 4; ++mm)
#pragma unroll
        for (int r = 0; r < 4; ++r) {
          int rloc = wr + mm * 16 + rg + r;
          size_t rowoff = (size_t)(bm + rloc) * 1024;
#pragma unroll
          for (int nn = 0; nn < 2; ++nn) {
            int d = nn * 16 + lr;
            float c = csf[rloc * 32 + d], s2 = snf[rloc * 32 + d];
            float lo = acc[mm][nn][r], hi = acc[mm][nn + 2][r];
            Cbuf[rowoff + colbase + nn * 16 + lr]      = f2b((lo * c - hi * s2) * sc);
            Cbuf[rowoff + colbase + nn * 16 + lr + 32] = f2b((hi * c + lo * s2) * sc);
          }
        }
    } else {
#pragma unroll
      for (int mm = 0; mm < 4; ++mm)
#pragma unroll
        for (int nn = 0; nn < 4; ++nn)
#pragma unroll
          for (int r = 0; r < 4; ++r)
            Cbuf[(size_t)(bm + wr + mm * 16 + rg + r) * 1024 + colbase + nn * 16 + lr] =
                f2b(acc[mm][nn][r]);
    }
  } else {
    float* C = (float*)Cv;
#pragma unroll
    for (int mm = 0; mm < 4; ++mm)
#pragma unroll
      for (int nn = 0; nn < 4; ++nn)
#pragma unroll
        for (int r = 0; r < 4; ++r)
          C[(size_t)(bm + wr + mm * 16 + rg + r) * 1024 + bnc + wc + nn * 16 + lr] =
              acc[mm][nn][r];
  }
}

// Causal flash attention v7: swapped-QK^T in-register softmax. P never leaves
// the owning lane: A-slot (hi4,e) <-> key 32kk+16(e>>2)+4*hi4+(e&3) (the
// lane's own p-values), and V is stored COLUMN-PERMUTED in LDS so the
// B-operand slot mapping matches: col(k) = 32(k>>5)+8((k>>2)&3)+4((k>>4)&1)+(k&3).
// 256 thr (4 waves x 32 q-rows), KVBLK=64 dbuf, LPT heavy-first, defer-max,
// exp2 domain, 2-deep shfl reduces only.
__global__ __launch_bounds__(256, 3) void attn_kernel(
    const unsigned short* __restrict__ Q,
    const unsigned short* __restrict__ K,
    const unsigned short* __restrict__ V,
    unsigned short* __restrict__ O) {
  __shared__ unsigned short Ks[2][64][72];   // [buf][key][d]
  __shared__ unsigned short Vt[2][64][72];   // [buf][d][permuted key col]
  const int tid = threadIdx.x, wave = tid >> 6, lane = tid & 63;
  const int idx = blockIdx.x;
  const int bh = idx & 127;
  const int b = bh >> 4, h = bh & 15;
  const int qb = 7 - (idx >> 7);             // heavy-first (LPT)
  const int tok0 = b << 10;
  const int lr = lane & 15, hi4 = lane >> 4, lk8 = hi4 << 3;
  const int rg = hi4 << 2;
  const int qrow0 = (qb << 7) + (wave << 5); // 32 rows per wave

  short8 qf[2][2];
#pragma unroll
  for (int mt = 0; mt < 2; ++mt) {
    const unsigned short* qp = &Q[(size_t)(tok0 + qrow0 + mt * 16 + lr) * 1024 + h * 64];
#pragma unroll
    for (int kk = 0; kk < 2; ++kk) qf[mt][kk] = *(const short8*)&qp[kk * 32 + lk8];
  }

  f32x4 acc[2][4] = {};
  float m[2], l[2];
#pragma unroll
  for (int mt = 0; mt < 2; ++mt) { m[mt] = -1e30f; l[mt] = 0.f; }

  // staging geometry (256 thr, 64-key tile)
  const int krow = tid >> 3, kcol = (tid & 7) << 3;  // K: rows krow, krow+32
  const int vd = lane;                               // V: d index
  const int baseC = ((wave & 1) << 4) + ((wave >> 1) << 2);  // perm col base
  short8 kst[2];
  short4v vst[4];

#define LOADT(kbx)                                                                 \
  do {                                                                             \
    const int kr0_ = tok0 + ((kbx) << 6);                                          \
    _Pragma("unroll") for (int it = 0; it < 2; ++it)                               \
        kst[it] = *(const short8*)&K[(size_t)(kr0_ + krow + it * 32) * 1024 +      \
                                     h * 64 + kcol];                               \
    _Pragma("unroll") for (int it = 0; it < 2; ++it) {                             \
      const unsigned short* vp_ =                                                  \
          &V[(size_t)(kr0_ + ((wave + it * 4) << 3)) * 1024 + h * 64 + vd];        \
      _Pragma("unroll") for (int i = 0; i < 4; ++i) {                              \
        vst[it * 2][i]     = (short)vp_[(size_t)i * 1024];                         \
        vst[it * 2 + 1][i] = (short)vp_[(size_t)(i + 4) * 1024];                   \
      }                                                                            \
    }                                                                              \
  } while (0)

#define STORET(bi)                                                                 \
  do {                                                                             \
    _Pragma("unroll") for (int it = 0; it < 2; ++it)                               \
        *(short8*)&Ks[bi][krow + it * 32][kcol] = kst[it];                         \
    *(short4v*)&Vt[bi][vd][baseC]          = vst[0];                               \
    *(short4v*)&Vt[bi][vd][baseC + 8]      = vst[1];                               \
    *(short4v*)&Vt[bi][vd][32 + baseC]     = vst[2];                               \
    *(short4v*)&Vt[bi][vd][32 + baseC + 8] = vst[3];                               \
  } while (0)

  const int nkb = (qb + 1) << 1;
  LOADT(0);
  STORET(0);
  __syncthreads();

  for (int kb = 0; kb < nkb; ++kb) {
    const int cur = kb & 1;
    const bool more = (kb + 1 < nkb);
    if (more) LOADT(kb + 1);  // VMEM in flight during compute (T14)

#pragma unroll
    for (int mt = 0; mt < 2; ++mt) {
      // swapped QK^T: p[ct][r] = S[key = ct*16 + 4*hi4 + r][q = lr]
      float p[4][4];
#pragma unroll
      for (int ct = 0; ct < 4; ++ct) {
        short8 kf0 = *(const short8*)&Ks[cur][ct * 16 + lr][lk8];
        short8 kf1 = *(const short8*)&Ks[cur][ct * 16 + lr][32 + lk8];
        f32x4 s = {};
        s = MFMA(kf0, qf[mt][0], s);
        s = MFMA(kf1, qf[mt][1], s);
#pragma unroll
        for (int r = 0; r < 4; ++r) p[ct][r] = s[r];
      }
      if (kb >= 2 * qb) {  // diagonal region: mask key > q
        const int qg = qrow0 + mt * 16 + lr;
#pragma unroll
        for (int ct = 0; ct < 4; ++ct)
#pragma unroll
          for (int r = 0; r < 4; ++r) {
            int kg = (kb << 6) + ct * 16 + rg + r;
            if (kg > qg) p[ct][r] = -1e30f;
          }
      }
      // row max: own 16 values + 2 shfl (lanes {lr, lr+16, lr+32, lr+48})
      float mx = p[0][0];
#pragma unroll
      for (int ct = 0; ct < 4; ++ct)
#pragma unroll
        for (int r = 0; r < 4; ++r) mx = fmaxf(mx, p[ct][r]);
      mx = fmaxf(mx, __shfl_xor(mx, 16));
      mx = fmaxf(mx, __shfl_xor(mx, 32));
      // defer-max (log2 units)
      if (__any(mx > m[mt] + 8.f)) {
        float mn = fmaxf(m[mt], mx);
        float alpha = __builtin_amdgcn_exp2f(m[mt] - mn);
        m[mt] = mn;
        l[mt] *= alpha;
        float a4[4];
#pragma unroll
        for (int r = 0; r < 4; ++r) a4[r] = __shfl(alpha, rg + r);
#pragma unroll
        for (int dt = 0; dt < 4; ++dt)
#pragma unroll
          for (int r = 0; r < 4; ++r) acc[mt][dt][r] *= a4[r];
      }
      // exp2 + pack: pk[ct][mm] = bf16{keys 16ct+4hi4+2mm, +1} for q=lr
      unsigned pk[4][2];
      float rs = 0.f;
#pragma unroll
      for (int ct = 0; ct < 4; ++ct) {
#pragma unroll
        for (int r = 0; r < 4; ++r) {
          p[ct][r] = __builtin_amdgcn_exp2f(p[ct][r] - m[mt]);
          rs += p[ct][r];
        }
        pk[ct][0] = ((unsigned)f2b(p[ct][1]) << 16) | f2b(p[ct][0]);
        pk[ct][1] = ((unsigned)f2b(p[ct][3]) << 16) | f2b(p[ct][2]);
      }
      // PV: A-operand = own pk (slot (hi4,e) <-> key 32kk+16(e>>2)+4hi4+(e&3));
      // Vt's permuted columns deliver matching keys at col kk*32+8*hi4+e.
#pragma unroll
      for (int kk = 0; kk < 2; ++kk) {
        union { unsigned u[4]; short8 v; } pa;
        pa.u[0] = pk[kk * 2][0];
        pa.u[1] = pk[kk * 2][1];
        pa.u[2] = pk[kk * 2 + 1][0];
        pa.u[3] = pk[kk * 2 + 1][1];
#pragma unroll
        for (int dt = 0; dt < 4; ++dt) {
          short8 vf = *(const short8*)&Vt[cur][dt * 16 + lr][kk * 32 + lk8];
          acc[mt][dt] = MFMA(pa.v, vf, acc[mt][dt]);
        }
      }
      // sum-reduce after PV issue (co-schedules under MFMA)
      rs += __shfl_xor(rs, 16);
      rs += __shfl_xor(rs, 32);
      l[mt] += rs;
    }

    if (more) {
      STORET(cur ^ 1);
      __syncthreads();
    }
  }
#undef LOADT
#undef STORET

#pragma unroll
  for (int mt = 0; mt < 2; ++mt) {
    float linv = 1.0f / l[mt];
    float inv[4];
#pragma unroll
    for (int r = 0; r < 4; ++r) inv[r] = __shfl(linv, rg + r);
#pragma unroll
    for (int dt = 0; dt < 4; ++dt)
#pragma unroll
      for (int r = 0; r < 4; ++r) {
        int trow = tok0 + qrow0 + mt * 16 + rg + r;
        O[(size_t)trow * 1024 + h * 64 + dt * 16 + lr] = f2b(acc[mt][dt][r] * inv[r]);
      }
  }
}

extern "C" void kernel_launch(void* const* d_in, const int* in_sizes, int n_in,
                              void* d_out, int out_size, void* d_ws, size_t ws_size,
                              hipStream_t stream) {
  const float* hidden = (const float*)d_in[0];
  const float* q_w    = (const float*)d_in[1];
  const float* k_w    = (const float*)d_in[2];
  const float* v_w    = (const float*)d_in[3];
  const float* o_w    = (const float*)d_in[4];
  const float* cosb   = (const float*)d_in[5];
  const float* sinb   = (const float*)d_in[6];

  const size_t TD = (size_t)8192 * 1024;
  unsigned short* ws  = (unsigned short*)d_ws;
  unsigned short* Qb  = ws;
  unsigned short* Kb  = ws + TD;
  unsigned short* Vb  = ws + 2 * TD;
  unsigned short* hBF = ws + 3 * TD;        // hidden bf16; aliased as AO after QKV
  unsigned short* wBF = ws + 4 * TD;        // q,k,v,o weights bf16 (4 x 1M)

  convert_kernel<<<4096, 256, 0, stream>>>(hidden, q_w, k_w, v_w, o_w, hBF);
  gemm256<true><<<dim3(32, 24), 512, 0, stream>>>(hBF, wBF, Qb, cosb, sinb);
  attn_kernel<<<1024, 256, 0, stream>>>(Qb, Kb, Vb, hBF /*AO*/);
  gemm256<false><<<dim3(32, 8), 512, 0, stream>>>(
      hBF, wBF + 3 * 1048576, d_out, nullptr, nullptr);
}